// Round 1
// baseline (649.639 us; speedup 1.0000x reference)
//
#include <hip/hip_runtime.h>

// LSTM: T=512, B=4096, I=10, H=20. fp32 throughout.
// One lane = one (batch, hidden-unit) pair, computes all 4 gates.
// One wave (64 lanes) = 3 batch elements (lanes 60..63 idle).
// Weights in registers (120 f32/lane); h broadcast via per-wave LDS row;
// x[t+1] prefetched into registers each step. No barriers in the loop
// (wave-lockstep gives read-before-write ordering on LDS for free).

constexpr int kT = 512;
constexpr int kB = 4096;
constexpr int kI = 10;
constexpr int kH = 20;

__device__ __forceinline__ float fsigmoid(float v) {
    // 1/(1+exp(-v)) via v_exp_f32 (2^x) + v_rcp_f32
    float e = __builtin_amdgcn_exp2f(-1.442695041f * v);
    return __builtin_amdgcn_rcpf(1.0f + e);
}
__device__ __forceinline__ float ftanh(float v) {
    // tanh(v) = 1 - 2/(exp(2v)+1); exp2-based. Saturates correctly at +-inf.
    float e = __builtin_amdgcn_exp2f(2.885390082f * v);
    return 1.0f - 2.0f * __builtin_amdgcn_rcpf(1.0f + e);
}

__global__ __launch_bounds__(64, 1) void lstm_fused(
    const float* __restrict__ x, const float* __restrict__ hx,
    const float* __restrict__ cx, const float* __restrict__ W_ih,
    const float* __restrict__ W_hh, const float* __restrict__ b_ih,
    const float* __restrict__ b_hh, float* __restrict__ out)
{
    __shared__ float h_s[4][kH];   // row 3 = scratch for idle lanes' g
    __shared__ float x_s[4][kI];

    const int lane = threadIdx.x;
    const int g = lane / kH;            // 0..3 (group within wave)
    const int u = lane - g * kH;        // 0..19 hidden unit
    const int b = blockIdx.x * 3 + g;
    const bool active = (lane < 60) && (b < kB);
    const int bc = active ? b : 0;      // clamped for safe loads

    // ---- weights -> registers (reused for all 512 steps) ----
    float Wih[4][kI], Whh[4][kH], bias[4];
    #pragma unroll
    for (int k = 0; k < 4; ++k) {
        const int row = k * kH + u;     // PyTorch gate order i,f,g,o
        #pragma unroll
        for (int i = 0; i < kI; ++i) Wih[k][i] = W_ih[row * kI + i];
        #pragma unroll
        for (int j = 0; j < kH; ++j) Whh[k][j] = W_hh[row * kH + j];
        bias[k] = b_ih[row] + b_hh[row];
    }

    float c = cx[bc * kH + u];
    if (active) {
        h_s[g][u] = hx[bc * kH + u];
        if (u < kI) x_s[g][u] = x[bc * kI + u];   // stage x[t=0]
    }
    __syncthreads();   // single wave: just orders initial LDS writes

    const float* xrow = x + (size_t)bc * kI;
    float* orow = out + (size_t)bc * kH + u;

    float xp = 0.0f;
    for (int t = 0; t < kT; ++t) {
        // prefetch x[t+1] into a register (latency hides under the FMAs)
        if (active && u < kI) {
            const int tn = (t + 1 < kT) ? (t + 1) : (kT - 1);
            xp = xrow[(size_t)tn * (kB * kI) + u];
        }
        if (active) {
            float a0 = bias[0], a1 = bias[1], a2 = bias[2], a3 = bias[3];
            #pragma unroll
            for (int i = 0; i < kI; ++i) {           // x projection (broadcast reads)
                const float xv = x_s[g][i];
                a0 = fmaf(Wih[0][i], xv, a0);
                a1 = fmaf(Wih[1][i], xv, a1);
                a2 = fmaf(Wih[2][i], xv, a2);
                a3 = fmaf(Wih[3][i], xv, a3);
            }
            #pragma unroll
            for (int j = 0; j < kH; ++j) {           // h projection (broadcast reads)
                const float hv = h_s[g][j];
                a0 = fmaf(Whh[0][j], hv, a0);
                a1 = fmaf(Whh[1][j], hv, a1);
                a2 = fmaf(Whh[2][j], hv, a2);
                a3 = fmaf(Whh[3][j], hv, a3);
            }
            const float ig = fsigmoid(a0);
            const float fg = fsigmoid(a1);
            const float gg = ftanh(a2);
            const float og = fsigmoid(a3);
            c = fmaf(fg, c, ig * gg);
            const float hn = og * ftanh(c);

            orow[(size_t)t * (kB * kH)] = hn;        // coalesced: 60 consecutive floats
            h_s[g][u] = hn;                          // after all h_s reads (in-order DS pipe)
            if (u < kI) x_s[g][u] = xp;              // x for t+1, after x_s reads
        }
    }
}

extern "C" void kernel_launch(void* const* d_in, const int* in_sizes, int n_in,
                              void* d_out, int out_size, void* d_ws, size_t ws_size,
                              hipStream_t stream) {
    const float* x    = (const float*)d_in[0];
    const float* hx   = (const float*)d_in[1];
    const float* cx   = (const float*)d_in[2];
    const float* W_ih = (const float*)d_in[3];
    const float* W_hh = (const float*)d_in[4];
    const float* b_ih = (const float*)d_in[5];
    const float* b_hh = (const float*)d_in[6];
    float* out = (float*)d_out;

    const int grid = (kB + 2) / 3;   // 1366 one-wave blocks, ~5.3 waves/CU
    lstm_fused<<<grid, 64, 0, stream>>>(x, hx, cx, W_ih, W_hh, b_ih, b_hh, out);
}

// Round 3
// 474.935 us; speedup vs baseline: 1.3678x; 1.3678x over previous
//
#include <hip/hip_runtime.h>

// LSTM T=512, B=4096, I=10, H=20, fp32.
// One lane = one (batch, unit, gate): 30 weights + bias in registers (no spill).
// Block = 320 threads = 4 batch x 20 units x 4 gates (5 waves, all lanes active).
// Gates of a unit are 4 adjacent lanes; i,f,g broadcast via ds_swizzle; c kept
// redundantly per lane; k==3 (o) lane computes h and stores. h/x double-buffered
// in LDS -> one __syncthreads per step. x[t+1] prefetched by lanes 0..39.

constexpr int kT = 512, kB = 4096, kI = 10, kH = 20;
constexpr int BPB = 4;                  // batch elements per block
constexpr int THREADS = BPB * kH * 4;   // 320 = 5 waves

__global__ __launch_bounds__(THREADS, 5) void lstm_gsplit(
    const float* __restrict__ x, const float* __restrict__ hx,
    const float* __restrict__ cx, const float* __restrict__ W_ih,
    const float* __restrict__ W_hh, const float* __restrict__ b_ih,
    const float* __restrict__ b_hh, float* __restrict__ out)
{
    __shared__ float h_s[2][BPB][kH];    // 640 B
    __shared__ float x_s[2][BPB][12];    // 384 B (rows padded to 12 -> 16B aligned)

    const int tid = threadIdx.x;
    const int b_loc = tid / 80;          // 0..3
    const int r = tid % 80;
    const int u = r >> 2;                // 0..19
    const int k = r & 3;                 // 0:i 1:f 2:g 3:o (PyTorch order)
    const int b0 = blockIdx.x * BPB;
    const int b = b0 + b_loc;
    const int row = k * kH + u;

    // ---- per-lane weights -> registers (reused 512 steps) ----
    float Wih[kI], Whh[kH];
    #pragma unroll
    for (int i = 0; i < kI; ++i) Wih[i] = W_ih[row * kI + i];
    #pragma unroll
    for (int j = 0; j < kH; ++j) Whh[j] = W_hh[row * kH + j];
    const float bias = b_ih[row] + b_hh[row];

    // unified activation: act = fma(rcp(1+exp2(c0*a)), c1, c2)
    // sigmoid: c0=-log2(e), c1=1, c2=0 ; tanh: c0=-2log2(e), c1=2, c2=-1
    const float c0 = (k == 2) ? -2.885390082f : -1.442695041f;
    const float c1 = (k == 2) ? 2.0f : 1.0f;
    const float c2 = (k == 2) ? -1.0f : 0.0f;

    float c = cx[(size_t)b * kH + u];

    // ---- initial staging ----
    if (tid < BPB * kI) x_s[0][tid / kI][tid % kI] = x[(size_t)b0 * kI + tid];
    if (tid < BPB * kH) h_s[0][tid / kH][tid % kH] = hx[(size_t)b0 * kH + tid];
    __syncthreads();

    const bool pf = (tid < BPB * kI);
    const int pb = tid / kI, pi = tid % kI;          // prefetch slot (valid if pf)
    const float* xpf = x + (size_t)kB * kI + (size_t)b0 * kI + tid;  // x[t=1] base
    float* outp = out + (size_t)b * kH + u;

    for (int t = 0; t < kT; ++t) {
        const int rb = t & 1, wb = rb ^ 1;

        // prefetch x[t+1] into a register; latency hides under the FMAs
        float xp = 0.0f;
        if (pf && (t + 1 < kT)) xp = *xpf;

        // gate pre-activation: 30 FMAs, LDS reads are 4-lane broadcasts
        float a = bias;
        #pragma unroll
        for (int i = 0; i < kI; ++i) a = fmaf(Wih[i], x_s[rb][b_loc][i], a);
        #pragma unroll
        for (int j = 0; j < kH; ++j) a = fmaf(Whh[j], h_s[rb][b_loc][j], a);

        float e = __builtin_amdgcn_exp2f(c0 * a);
        float act = fmaf(__builtin_amdgcn_rcpf(1.0f + e), c1, c2);

        // broadcast gate q of each 4-lane group: pattern (q<<5)|0x1C (BitMode)
        const int ai = __float_as_int(act);
        const float iv = __int_as_float(__builtin_amdgcn_ds_swizzle(ai, 0x001C));
        const float fv = __int_as_float(__builtin_amdgcn_ds_swizzle(ai, 0x003C));
        const float gv = __int_as_float(__builtin_amdgcn_ds_swizzle(ai, 0x005C));

        c = fmaf(fv, c, iv * gv);                    // redundant in all 4 lanes
        float e2 = __builtin_amdgcn_exp2f(-2.885390082f * c);
        float th = fmaf(__builtin_amdgcn_rcpf(1.0f + e2), 2.0f, -1.0f);
        float hn = act * th;                         // valid on k==3 (act==o)

        if (k == 3) {
            h_s[wb][b_loc][u] = hn;
            *outp = hn;                              // coalesced within block range
        }
        if (pf) x_s[wb][pb][pi] = xp;

        outp += (size_t)kB * kH;
        xpf  += (size_t)kB * kI;
        __syncthreads();                             // writes -> next step's reads
    }
}

extern "C" void kernel_launch(void* const* d_in, const int* in_sizes, int n_in,
                              void* d_out, int out_size, void* d_ws, size_t ws_size,
                              hipStream_t stream) {
    const float* x    = (const float*)d_in[0];
    const float* hx   = (const float*)d_in[1];
    const float* cx   = (const float*)d_in[2];
    const float* W_ih = (const float*)d_in[3];
    const float* W_hh = (const float*)d_in[4];
    const float* b_ih = (const float*)d_in[5];
    const float* b_hh = (const float*)d_in[6];
    float* out = (float*)d_out;

    lstm_gsplit<<<kB / BPB, THREADS, 0, stream>>>(x, hx, cx, W_ih, W_hh, b_ih, b_hh, out);
}